// Round 15
// baseline (207.333 us; speedup 1.0000x reference)
//
#include <hip/hip_runtime.h>
#include <hip/hip_fp16.h>

#define NN 100000
#define HC 128
#define NE 1600000

typedef float f32x4 __attribute__((ext_vector_type(4)));
typedef short bf16x8 __attribute__((ext_vector_type(8)));

// round-to-nearest-even float -> bf16 (bit trick; inputs are tame, no NaN/Inf)
__device__ __forceinline__ unsigned short f2bf(float f) {
  union { float f; unsigned u; } c; c.f = f;
  unsigned u = c.u + (0x7FFFu + ((c.u >> 16) & 1u));
  return (unsigned short)(u >> 16);
}
__device__ __forceinline__ float bf2f(unsigned short b) {
  union { unsigned u; float f; } c; c.u = ((unsigned)b) << 16;
  return c.f;
}

// ---------------------------------------------------------------------------
// Prep: W in MFMA-FRAGMENT order, split bf16 hi/lo (unchanged).
// frag f = (ot*4 + kg)*64 + lane; element e: o = ot*16 + (lane&15),
// k = kg*32 + (lane>>4)*8 + e.
// ---------------------------------------------------------------------------
__global__ __launch_bounds__(256) void wprep2_kernel(
    const float* __restrict__ W1, unsigned short* __restrict__ Whf,
    unsigned short* __restrict__ Wlf) {
  const int f = blockIdx.x * 256 + threadIdx.x;  // over 16*4*64 = 4096 frags
  if (f >= 4096) return;
  const int lane = f & 63;
  const int kg = (f >> 6) & 3;
  const int ot = f >> 8;
  const int lr = lane & 15;
  const int lg = lane >> 4;
  const int o = ot * 16 + lr;
  const int kb = kg * 32 + lg * 8;
  const float* __restrict__ src =
      W1 + (size_t)(o & 127) * 256 + ((o >> 7) << 7) + kb;
#pragma unroll
  for (int e = 0; e < 8; ++e) {
    const float v = src[e];
    const unsigned short hi = f2bf(v);
    Whf[(size_t)f * 8 + e] = hi;
    Wlf[(size_t)f * 8 + e] = f2bf(v - bf2f(hi));
  }
}

// ---------------------------------------------------------------------------
// Stage 1 (MFMA bf16x3, LOW-VGPR): r12 structure (proven best) restructured
// so only ONE node-subtile's fragments are live at a time (32 VGPR instead
// of 64) and capped at 8 waves/SIMD via launch_bounds. W fragments re-read
// per subtile (L2-hit, cheap). Accumulation order per acc unchanged ->
// bit-identical to r12. Theory: VGPR 84 rounds to the 128-granule (m69) and
// halves the wave budget; <=64 doubles it.
// ---------------------------------------------------------------------------
__global__ __launch_bounds__(256, 8) void precompute_uv_mfma8_kernel(
    const float* __restrict__ z, const unsigned short* __restrict__ Whf,
    const unsigned short* __restrict__ Wlf, __half* __restrict__ UV) {
  __shared__ char zs[16384];  // 32 nodes x 128 floats, XOR-swizzled rows

  const int t = threadIdx.x;
  const int lane = t & 63;
  const int wv = t >> 6;                 // wave 0..3 -> output quarter
  const int nb = blockIdx.x * 32;        // block's node base (NN%32==0)
  const int lr = lane & 15;
  const int lg = lane >> 4;

  // ---- stage z tile: coalesced float4, XOR-swizzled rows ----
#pragma unroll
  for (int i = 0; i < 4; ++i) {
    const int ci = t + 256 * i;          // chunk index 0..1023
    const int row = ci >> 5;
    const int c16 = ci & 31;
    const float4 v = *(const float4*)(z + (size_t)(nb + row) * HC + c16 * 4);
    const int dst = (row * 512 + c16 * 16) ^ ((row & 7) << 4);
    *(float4*)(zs + dst) = v;
  }
  __syncthreads();

  // ---- per node-subtile: frags (8 bf16x8 live) then 4 o-tiles of MFMA ----
#pragma unroll 1
  for (int ms = 0; ms < 2; ++ms) {
    bf16x8 bh[4], bl[4];
    {
      const int row = ms * 16 + lr;
      const int sw = (row & 7) << 4;
#pragma unroll
      for (int kg = 0; kg < 4; ++kg) {
        const int c16 = kg * 8 + lg * 2;
        const float4 p0 = *(const float4*)(zs + ((row * 512 + c16 * 16) ^ sw));
        const float4 p1 = *(const float4*)(zs + ((row * 512 + (c16 + 1) * 16) ^ sw));
        const float v[8] = {p0.x, p0.y, p0.z, p0.w, p1.x, p1.y, p1.z, p1.w};
#pragma unroll
        for (int e = 0; e < 8; ++e) {
          const unsigned short hi = f2bf(v[e]);
          bh[kg][e] = (short)hi;
          bl[kg][e] = (short)f2bf(v[e] - bf2f(hi));
        }
      }
    }

#pragma unroll 1
    for (int nt = 0; nt < 4; ++nt) {
      const int ot = wv * 4 + nt;        // global o-tile
      const unsigned short* __restrict__ wph =
          Whf + ((size_t)(ot * 4) * 64 + lane) * 8;
      const unsigned short* __restrict__ wpl =
          Wlf + ((size_t)(ot * 4) * 64 + lane) * 8;

      f32x4 acc = {0.f, 0.f, 0.f, 0.f};
#pragma unroll
      for (int kg = 0; kg < 4; ++kg) {
        const bf16x8 ah = *(const bf16x8*)(wph + (size_t)kg * 64 * 8);
        const bf16x8 al = *(const bf16x8*)(wpl + (size_t)kg * 64 * 8);
        acc = __builtin_amdgcn_mfma_f32_16x16x32_bf16(ah, bh[kg], acc, 0, 0, 0);
        acc = __builtin_amdgcn_mfma_f32_16x16x32_bf16(al, bh[kg], acc, 0, 0, 0);
        acc = __builtin_amdgcn_mfma_f32_16x16x32_bf16(ah, bl[kg], acc, 0, 0, 0);
      }

      // packed store: lane holds o = ot*16 + lg*4 + (0..3) for its node
      const int node = nb + ms * 16 + lr;
      union { uint2 u; __half2 h[2]; } pk;
      pk.h[0] = __floats2half2_rn(acc[0], acc[1]);
      pk.h[1] = __floats2half2_rn(acc[2], acc[3]);
      *(uint2*)(UV + (size_t)node * 256 + ot * 16 + lg * 4) = pk.u;
    }
  }
}

// ---------------------------------------------------------------------------
// Stage 2: per-edge decode from fp16 UV over [e0, e1) (3-way split keeps
// stage 1 rank-1 in the rocprof top-5). 16 lanes/edge; lane owns o=8l..8l+7.
// ---------------------------------------------------------------------------
__global__ __launch_bounds__(256) void edge_decode_f16_kernel(
    const int* __restrict__ eidx, const __half* __restrict__ UV,
    const float* __restrict__ b1, const float* __restrict__ W2,
    const float* __restrict__ b2, float* __restrict__ out,
    int e0, int e1) {
  const int lane = threadIdx.x & 15;
  const int qw = (blockIdx.x * 256 + threadIdx.x) >> 4;
  const int nqw = (gridDim.x * 256) >> 4;

  const float4 b1a = ((const float4*)b1)[2 * lane];
  const float4 b1b = ((const float4*)b1)[2 * lane + 1];
  const float4 w2a = ((const float4*)W2)[2 * lane];
  const float4 w2b = ((const float4*)W2)[2 * lane + 1];
  const float bb[8] = {b1a.x, b1a.y, b1a.z, b1a.w, b1b.x, b1b.y, b1b.z, b1b.w};
  const float ww[8] = {w2a.x, w2a.y, w2a.z, w2a.w, w2b.x, w2b.y, w2b.z, w2b.w};
  const float bias2 = b2[0];

  const int* __restrict__ rows = eidx;
  const int* __restrict__ cols = eidx + NE;

#pragma unroll 2
  for (int e = e0 + qw; e < e1; e += nqw) {
    const int r = rows[e];
    const int c = cols[e];
    union { uint4 u; __half2 h[4]; } Uu, Vv;
    Uu.u = *(const uint4*)(UV + (size_t)r * 256 + lane * 8);
    Vv.u = *(const uint4*)(UV + (size_t)c * 256 + 128 + lane * 8);

    float s = 0.f;
#pragma unroll
    for (int k = 0; k < 4; ++k) {
      const float2 uf = __half22float2(Uu.h[k]);
      const float2 vf = __half22float2(Vv.h[k]);
      float t0 = uf.x + vf.x + bb[2 * k];
      t0 = (t0 >= 0.f) ? t0 : 0.01f * t0;
      s = fmaf(t0, ww[2 * k], s);
      float t1 = uf.y + vf.y + bb[2 * k + 1];
      t1 = (t1 >= 0.f) ? t1 : 0.01f * t1;
      s = fmaf(t1, ww[2 * k + 1], s);
    }

    s += __shfl_xor(s, 8);
    s += __shfl_xor(s, 4);
    s += __shfl_xor(s, 2);
    s += __shfl_xor(s, 1);
    if (lane == 0) out[e] = s + bias2;
  }
}

// ---------------------------------------------------------------------------
// Fallback (only if workspace is too small): direct per-edge fp32 compute.
// ---------------------------------------------------------------------------
__global__ __launch_bounds__(64) void edge_direct_kernel(
    const float* __restrict__ z, const int* __restrict__ eidx,
    const float* __restrict__ W1, const float* __restrict__ b1,
    const float* __restrict__ W2, const float* __restrict__ b2,
    float* __restrict__ out) {
  const int lane = threadIdx.x;
  const int o0 = lane, o1 = lane + 64;
  const float w2_0 = W2[o0], w2_1 = W2[o1];
  const float b1_0 = b1[o0], b1_1 = b1[o1];
  const float bias2 = b2[0];

  for (int e = blockIdx.x; e < NE; e += gridDim.x) {
    const int r = eidx[e];
    const int c = eidx[e + NE];
    const float* __restrict__ zr = z + (size_t)r * HC;
    const float* __restrict__ zc = z + (size_t)c * HC;
    float a0 = 0.f, a1 = 0.f;
    for (int h = 0; h < HC; ++h) {
      const float zrh = zr[h], zch = zc[h];
      a0 = fmaf(zrh, W1[(size_t)o0 * 256 + h], a0);
      a0 = fmaf(zch, W1[(size_t)o0 * 256 + 128 + h], a0);
      a1 = fmaf(zrh, W1[(size_t)o1 * 256 + h], a1);
      a1 = fmaf(zch, W1[(size_t)o1 * 256 + 128 + h], a1);
    }
    a0 += b1_0; a1 += b1_1;
    a0 = (a0 >= 0.f) ? a0 : 0.01f * a0;
    a1 = (a1 >= 0.f) ? a1 : 0.01f * a1;
    float s = fmaf(a0, w2_0, a1 * w2_1);
    for (int off = 32; off >= 1; off >>= 1) s += __shfl_xor(s, off);
    if (lane == 0) out[e] = s + bias2;
  }
}

extern "C" void kernel_launch(void* const* d_in, const int* in_sizes, int n_in,
                              void* d_out, int out_size, void* d_ws, size_t ws_size,
                              hipStream_t stream) {
  const float* z  = (const float*)d_in[0];
  const int*   ei = (const int*)d_in[1];
  const float* W1 = (const float*)d_in[2];
  const float* b1 = (const float*)d_in[3];
  const float* W2 = (const float*)d_in[4];
  const float* b2 = (const float*)d_in[5];
  float* out = (float*)d_out;

  const size_t uv_bytes = (size_t)NN * 256 * sizeof(__half);          // 51,200,000
  const size_t w_bytes  = (size_t)256 * 128 * sizeof(unsigned short); // 65,536 each

  if (ws_size >= uv_bytes + 2 * w_bytes) {
    __half* UV = (__half*)d_ws;
    unsigned short* Whf = (unsigned short*)((char*)d_ws + uv_bytes);
    unsigned short* Wlf = Whf + 256 * 128;
    wprep2_kernel<<<16, 256, 0, stream>>>(W1, Whf, Wlf);
    precompute_uv_mfma8_kernel<<<NN / 32, 256, 0, stream>>>(z, Whf, Wlf, UV);
    int bounds[4] = {0, NE / 3, 2 * (NE / 3), NE};
    for (int q = 0; q < 3; ++q) {
      edge_decode_f16_kernel<<<2048, 256, 0, stream>>>(
          ei, UV, b1, W2, b2, out, bounds[q], bounds[q + 1]);
    }
  } else {
    edge_direct_kernel<<<8192, 64, 0, stream>>>(z, ei, W1, b1, W2, b2, out);
  }
}

// Round 18
// 167.549 us; speedup vs baseline: 1.2374x; 1.2374x over previous
//
#include <hip/hip_runtime.h>
#include <hip/hip_fp16.h>

#define NN 100000
#define HC 128
#define NE 1600000

typedef float f32x4 __attribute__((ext_vector_type(4)));
typedef short bf16x8 __attribute__((ext_vector_type(8)));

// round-to-nearest-even float -> bf16 (bit trick; inputs are tame, no NaN/Inf)
__device__ __forceinline__ unsigned short f2bf(float f) {
  union { float f; unsigned u; } c; c.f = f;
  unsigned u = c.u + (0x7FFFu + ((c.u >> 16) & 1u));
  return (unsigned short)(u >> 16);
}
__device__ __forceinline__ float bf2f(unsigned short b) {
  union { unsigned u; float f; } c; c.u = ((unsigned)b) << 16;
  return c.f;
}

// ---------------------------------------------------------------------------
// Prep: W in MFMA-FRAGMENT order, split bf16 hi/lo (unchanged).
// frag f = (ot*4 + kg)*64 + lane; element e: o = ot*16 + (lane&15),
// k = kg*32 + (lane>>4)*8 + e.
// ---------------------------------------------------------------------------
__global__ __launch_bounds__(256) void wprep2_kernel(
    const float* __restrict__ W1, unsigned short* __restrict__ Whf,
    unsigned short* __restrict__ Wlf) {
  const int f = blockIdx.x * 256 + threadIdx.x;  // over 16*4*64 = 4096 frags
  if (f >= 4096) return;
  const int lane = f & 63;
  const int kg = (f >> 6) & 3;
  const int ot = f >> 8;
  const int lr = lane & 15;
  const int lg = lane >> 4;
  const int o = ot * 16 + lr;
  const int kb = kg * 32 + lg * 8;
  const float* __restrict__ src =
      W1 + (size_t)(o & 127) * 256 + ((o >> 7) << 7) + kb;
#pragma unroll
  for (int e = 0; e < 8; ++e) {
    const float v = src[e];
    const unsigned short hi = f2bf(v);
    Whf[(size_t)f * 8 + e] = hi;
    Wlf[(size_t)f * 8 + e] = f2bf(v - bf2f(hi));
  }
}

// ---------------------------------------------------------------------------
// Stage 1 (MFMA bf16x3): r12's proven kernel, VERBATIM (45 us, VGPR 84).
// Six alternatives tested (r5/r7/r9/r13/r14/r15) all neutral-or-worse;
// this is the plateau configuration. Do not "improve" without new evidence.
// ---------------------------------------------------------------------------
__global__ __launch_bounds__(256) void precompute_uv_mfma5_kernel(
    const float* __restrict__ z, const unsigned short* __restrict__ Whf,
    const unsigned short* __restrict__ Wlf, __half* __restrict__ UV) {
  __shared__ char zs[32 * 512];  // 32 nodes x 128 floats, XOR-swizzled rows

  const int t = threadIdx.x;
  const int lane = t & 63;
  const int wv = t >> 6;                 // wave 0..3 -> output quarter
  const int nb = blockIdx.x * 32;        // block's node base (NN%32==0)
  const int lr = lane & 15;
  const int lg = lane >> 4;

  // ---- stage z tile: 32 rows x 32 float4-chunks, coalesced, swizzled ----
#pragma unroll
  for (int i = 0; i < 4; ++i) {
    const int ci = t + 256 * i;          // chunk index 0..1023
    const int row = ci >> 5;
    const int c16 = ci & 31;
    const float4 v = *(const float4*)(z + (size_t)(nb + row) * HC + c16 * 4);
    const int dst = (row * 512 + c16 * 16) ^ ((row & 7) << 4);
    *(float4*)(zs + dst) = v;
  }
  __syncthreads();

  // ---- z fragments (B): 2 node-subtiles x 4 k-groups via ds_read_b128 ----
  bf16x8 bh[2][4], bl[2][4];
#pragma unroll
  for (int ms = 0; ms < 2; ++ms) {
    const int row = ms * 16 + lr;
    const int sw = (row & 7) << 4;
#pragma unroll
    for (int kg = 0; kg < 4; ++kg) {
      const int c16 = kg * 8 + lg * 2;
      const float4 p0 = *(const float4*)(zs + ((row * 512 + c16 * 16) ^ sw));
      const float4 p1 = *(const float4*)(zs + ((row * 512 + (c16 + 1) * 16) ^ sw));
      const float v[8] = {p0.x, p0.y, p0.z, p0.w, p1.x, p1.y, p1.z, p1.w};
#pragma unroll
      for (int e = 0; e < 8; ++e) {
        const unsigned short hi = f2bf(v[e]);
        bh[ms][kg][e] = (short)hi;
        bl[ms][kg][e] = (short)f2bf(v[e] - bf2f(hi));
      }
    }
  }

  // ---- loop over this wave's 4 output tiles of 16 ----
#pragma unroll 1
  for (int nt = 0; nt < 4; ++nt) {
    const int ot = wv * 4 + nt;          // global o-tile
    const unsigned short* __restrict__ wph = Whf + ((size_t)(ot * 4) * 64 + lane) * 8;
    const unsigned short* __restrict__ wpl = Wlf + ((size_t)(ot * 4) * 64 + lane) * 8;

    f32x4 acc0 = {0.f, 0.f, 0.f, 0.f};  // node-subtile 0
    f32x4 acc1 = {0.f, 0.f, 0.f, 0.f};  // node-subtile 1
#pragma unroll
    for (int kg = 0; kg < 4; ++kg) {
      const bf16x8 ah = *(const bf16x8*)(wph + (size_t)kg * 64 * 8);
      const bf16x8 al = *(const bf16x8*)(wpl + (size_t)kg * 64 * 8);
      acc0 = __builtin_amdgcn_mfma_f32_16x16x32_bf16(ah, bh[0][kg], acc0, 0, 0, 0);
      acc0 = __builtin_amdgcn_mfma_f32_16x16x32_bf16(al, bh[0][kg], acc0, 0, 0, 0);
      acc0 = __builtin_amdgcn_mfma_f32_16x16x32_bf16(ah, bl[0][kg], acc0, 0, 0, 0);
      acc1 = __builtin_amdgcn_mfma_f32_16x16x32_bf16(ah, bh[1][kg], acc1, 0, 0, 0);
      acc1 = __builtin_amdgcn_mfma_f32_16x16x32_bf16(al, bh[1][kg], acc1, 0, 0, 0);
      acc1 = __builtin_amdgcn_mfma_f32_16x16x32_bf16(ah, bl[1][kg], acc1, 0, 0, 0);
    }

    // ---- packed store: lane holds o = ot*16 + lg*4 + (0..3) for its node ----
    const int ob = ot * 16 + lg * 4;
    {
      const int node = nb + lr;
      union { uint2 u; __half2 h[2]; } pk;
      pk.h[0] = __floats2half2_rn(acc0[0], acc0[1]);
      pk.h[1] = __floats2half2_rn(acc0[2], acc0[3]);
      *(uint2*)(UV + (size_t)node * 256 + ob) = pk.u;
    }
    {
      const int node = nb + 16 + lr;
      union { uint2 u; __half2 h[2]; } pk;
      pk.h[0] = __floats2half2_rn(acc1[0], acc1[1]);
      pk.h[1] = __floats2half2_rn(acc1[2], acc1[3]);
      *(uint2*)(UV + (size_t)node * 256 + ob) = pk.u;
    }
  }
}

// ---------------------------------------------------------------------------
// Stage 2 v2: 8 lanes per edge (was 16). Lane oct owns o = 16*oct..16*oct+15
// of each 128-dim half; loads 2x uint4 U + 2x uint4 V (same bytes/edge, half
// the iterations, 3-stage reduce instead of 4). Single dispatch.
// ---------------------------------------------------------------------------
__global__ __launch_bounds__(256) void edge_decode_f16v2_kernel(
    const int* __restrict__ eidx, const __half* __restrict__ UV,
    const float* __restrict__ b1, const float* __restrict__ W2,
    const float* __restrict__ b2, float* __restrict__ out) {
  const int oct = threadIdx.x & 7;
  const int eg = (blockIdx.x * 256 + threadIdx.x) >> 3;
  const int negs = (gridDim.x * 256) >> 3;

  // loop-invariant: lane's 16 b1/w2 values (o = 16*oct .. 16*oct+15)
  float bb[16], ww[16];
#pragma unroll
  for (int i = 0; i < 4; ++i) {
    const float4 b = ((const float4*)b1)[4 * oct + i];
    const float4 w = ((const float4*)W2)[4 * oct + i];
    bb[4 * i + 0] = b.x; bb[4 * i + 1] = b.y; bb[4 * i + 2] = b.z; bb[4 * i + 3] = b.w;
    ww[4 * i + 0] = w.x; ww[4 * i + 1] = w.y; ww[4 * i + 2] = w.z; ww[4 * i + 3] = w.w;
  }
  const float bias2 = b2[0];

  const int* __restrict__ rows = eidx;
  const int* __restrict__ cols = eidx + NE;

#pragma unroll 2
  for (int e = eg; e < NE; e += negs) {
    const int r = rows[e];
    const int c = cols[e];
    union { uint4 u[2]; __half2 h[8]; } Uu, Vv;
    Uu.u[0] = *(const uint4*)(UV + (size_t)r * 256 + oct * 16);
    Uu.u[1] = *(const uint4*)(UV + (size_t)r * 256 + oct * 16 + 8);
    Vv.u[0] = *(const uint4*)(UV + (size_t)c * 256 + 128 + oct * 16);
    Vv.u[1] = *(const uint4*)(UV + (size_t)c * 256 + 128 + oct * 16 + 8);

    float s = 0.f;
#pragma unroll
    for (int k = 0; k < 8; ++k) {
      const float2 uf = __half22float2(Uu.h[k]);
      const float2 vf = __half22float2(Vv.h[k]);
      float t0 = uf.x + vf.x + bb[2 * k];
      t0 = (t0 >= 0.f) ? t0 : 0.01f * t0;
      s = fmaf(t0, ww[2 * k], s);
      float t1 = uf.y + vf.y + bb[2 * k + 1];
      t1 = (t1 >= 0.f) ? t1 : 0.01f * t1;
      s = fmaf(t1, ww[2 * k + 1], s);
    }

    // reduce across the 8-lane group (xor masks <= 4 stay in-group)
    s += __shfl_xor(s, 4);
    s += __shfl_xor(s, 2);
    s += __shfl_xor(s, 1);
    if (oct == 0) out[e] = s + bias2;
  }
}

// ---------------------------------------------------------------------------
// Fallback (only if workspace is too small): direct per-edge fp32 compute.
// ---------------------------------------------------------------------------
__global__ __launch_bounds__(64) void edge_direct_kernel(
    const float* __restrict__ z, const int* __restrict__ eidx,
    const float* __restrict__ W1, const float* __restrict__ b1,
    const float* __restrict__ W2, const float* __restrict__ b2,
    float* __restrict__ out) {
  const int lane = threadIdx.x;
  const int o0 = lane, o1 = lane + 64;
  const float w2_0 = W2[o0], w2_1 = W2[o1];
  const float b1_0 = b1[o0], b1_1 = b1[o1];
  const float bias2 = b2[0];

  for (int e = blockIdx.x; e < NE; e += gridDim.x) {
    const int r = eidx[e];
    const int c = eidx[e + NE];
    const float* __restrict__ zr = z + (size_t)r * HC;
    const float* __restrict__ zc = z + (size_t)c * HC;
    float a0 = 0.f, a1 = 0.f;
    for (int h = 0; h < HC; ++h) {
      const float zrh = zr[h], zch = zc[h];
      a0 = fmaf(zrh, W1[(size_t)o0 * 256 + h], a0);
      a0 = fmaf(zch, W1[(size_t)o0 * 256 + 128 + h], a0);
      a1 = fmaf(zrh, W1[(size_t)o1 * 256 + h], a1);
      a1 = fmaf(zch, W1[(size_t)o1 * 256 + 128 + h], a1);
    }
    a0 += b1_0; a1 += b1_1;
    a0 = (a0 >= 0.f) ? a0 : 0.01f * a0;
    a1 = (a1 >= 0.f) ? a1 : 0.01f * a1;
    float s = fmaf(a0, w2_0, a1 * w2_1);
    for (int off = 32; off >= 1; off >>= 1) s += __shfl_xor(s, off);
    if (lane == 0) out[e] = s + bias2;
  }
}

extern "C" void kernel_launch(void* const* d_in, const int* in_sizes, int n_in,
                              void* d_out, int out_size, void* d_ws, size_t ws_size,
                              hipStream_t stream) {
  const float* z  = (const float*)d_in[0];
  const int*   ei = (const int*)d_in[1];
  const float* W1 = (const float*)d_in[2];
  const float* b1 = (const float*)d_in[3];
  const float* W2 = (const float*)d_in[4];
  const float* b2 = (const float*)d_in[5];
  float* out = (float*)d_out;

  const size_t uv_bytes = (size_t)NN * 256 * sizeof(__half);          // 51,200,000
  const size_t w_bytes  = (size_t)256 * 128 * sizeof(unsigned short); // 65,536 each

  if (ws_size >= uv_bytes + 2 * w_bytes) {
    __half* UV = (__half*)d_ws;
    unsigned short* Whf = (unsigned short*)((char*)d_ws + uv_bytes);
    unsigned short* Wlf = Whf + 256 * 128;
    wprep2_kernel<<<16, 256, 0, stream>>>(W1, Whf, Wlf);
    precompute_uv_mfma5_kernel<<<NN / 32, 256, 0, stream>>>(z, Whf, Wlf, UV);
    edge_decode_f16v2_kernel<<<2048, 256, 0, stream>>>(ei, UV, b1, W2, b2, out);
  } else {
    edge_direct_kernel<<<8192, 64, 0, stream>>>(z, ei, W1, b1, W2, b2, out);
  }
}

// Round 19
// 156.179 us; speedup vs baseline: 1.3275x; 1.0728x over previous
//
#include <hip/hip_runtime.h>
#include <hip/hip_fp16.h>

#define NN 100000
#define HC 128
#define NE 1600000

typedef float f32x4 __attribute__((ext_vector_type(4)));
typedef short bf16x8 __attribute__((ext_vector_type(8)));

// round-to-nearest-even float -> bf16 (bit trick; inputs are tame, no NaN/Inf)
__device__ __forceinline__ unsigned short f2bf(float f) {
  union { float f; unsigned u; } c; c.f = f;
  unsigned u = c.u + (0x7FFFu + ((c.u >> 16) & 1u));
  return (unsigned short)(u >> 16);
}
__device__ __forceinline__ float bf2f(unsigned short b) {
  union { unsigned u; float f; } c; c.u = ((unsigned)b) << 16;
  return c.f;
}

// ---------------------------------------------------------------------------
// Prep: W in MFMA-FRAGMENT order, split bf16 hi/lo (unchanged).
// frag f = (ot*4 + kg)*64 + lane; element e: o = ot*16 + (lane&15),
// k = kg*32 + (lane>>4)*8 + e.
// ---------------------------------------------------------------------------
__global__ __launch_bounds__(256) void wprep2_kernel(
    const float* __restrict__ W1, unsigned short* __restrict__ Whf,
    unsigned short* __restrict__ Wlf) {
  const int f = blockIdx.x * 256 + threadIdx.x;  // over 16*4*64 = 4096 frags
  if (f >= 4096) return;
  const int lane = f & 63;
  const int kg = (f >> 6) & 3;
  const int ot = f >> 8;
  const int lr = lane & 15;
  const int lg = lane >> 4;
  const int o = ot * 16 + lr;
  const int kb = kg * 32 + lg * 8;
  const float* __restrict__ src =
      W1 + (size_t)(o & 127) * 256 + ((o >> 7) << 7) + kb;
#pragma unroll
  for (int e = 0; e < 8; ++e) {
    const float v = src[e];
    const unsigned short hi = f2bf(v);
    Whf[(size_t)f * 8 + e] = hi;
    Wlf[(size_t)f * 8 + e] = f2bf(v - bf2f(hi));
  }
}

// ---------------------------------------------------------------------------
// Stage 1 (MFMA bf16x3): r12's proven kernel, VERBATIM (45 us, VGPR 84).
// Seven alternatives tested (r5/r7/r9/r13/r14/r15) all neutral-or-worse.
// ---------------------------------------------------------------------------
__global__ __launch_bounds__(256) void precompute_uv_mfma5_kernel(
    const float* __restrict__ z, const unsigned short* __restrict__ Whf,
    const unsigned short* __restrict__ Wlf, __half* __restrict__ UV) {
  __shared__ char zs[32 * 512];  // 32 nodes x 128 floats, XOR-swizzled rows

  const int t = threadIdx.x;
  const int lane = t & 63;
  const int wv = t >> 6;                 // wave 0..3 -> output quarter
  const int nb = blockIdx.x * 32;        // block's node base (NN%32==0)
  const int lr = lane & 15;
  const int lg = lane >> 4;

  // ---- stage z tile: 32 rows x 32 float4-chunks, coalesced, swizzled ----
#pragma unroll
  for (int i = 0; i < 4; ++i) {
    const int ci = t + 256 * i;          // chunk index 0..1023
    const int row = ci >> 5;
    const int c16 = ci & 31;
    const float4 v = *(const float4*)(z + (size_t)(nb + row) * HC + c16 * 4);
    const int dst = (row * 512 + c16 * 16) ^ ((row & 7) << 4);
    *(float4*)(zs + dst) = v;
  }
  __syncthreads();

  // ---- z fragments (B): 2 node-subtiles x 4 k-groups via ds_read_b128 ----
  bf16x8 bh[2][4], bl[2][4];
#pragma unroll
  for (int ms = 0; ms < 2; ++ms) {
    const int row = ms * 16 + lr;
    const int sw = (row & 7) << 4;
#pragma unroll
    for (int kg = 0; kg < 4; ++kg) {
      const int c16 = kg * 8 + lg * 2;
      const float4 p0 = *(const float4*)(zs + ((row * 512 + c16 * 16) ^ sw));
      const float4 p1 = *(const float4*)(zs + ((row * 512 + (c16 + 1) * 16) ^ sw));
      const float v[8] = {p0.x, p0.y, p0.z, p0.w, p1.x, p1.y, p1.z, p1.w};
#pragma unroll
      for (int e = 0; e < 8; ++e) {
        const unsigned short hi = f2bf(v[e]);
        bh[ms][kg][e] = (short)hi;
        bl[ms][kg][e] = (short)f2bf(v[e] - bf2f(hi));
      }
    }
  }

  // ---- loop over this wave's 4 output tiles of 16 ----
#pragma unroll 1
  for (int nt = 0; nt < 4; ++nt) {
    const int ot = wv * 4 + nt;          // global o-tile
    const unsigned short* __restrict__ wph = Whf + ((size_t)(ot * 4) * 64 + lane) * 8;
    const unsigned short* __restrict__ wpl = Wlf + ((size_t)(ot * 4) * 64 + lane) * 8;

    f32x4 acc0 = {0.f, 0.f, 0.f, 0.f};  // node-subtile 0
    f32x4 acc1 = {0.f, 0.f, 0.f, 0.f};  // node-subtile 1
#pragma unroll
    for (int kg = 0; kg < 4; ++kg) {
      const bf16x8 ah = *(const bf16x8*)(wph + (size_t)kg * 64 * 8);
      const bf16x8 al = *(const bf16x8*)(wpl + (size_t)kg * 64 * 8);
      acc0 = __builtin_amdgcn_mfma_f32_16x16x32_bf16(ah, bh[0][kg], acc0, 0, 0, 0);
      acc0 = __builtin_amdgcn_mfma_f32_16x16x32_bf16(al, bh[0][kg], acc0, 0, 0, 0);
      acc0 = __builtin_amdgcn_mfma_f32_16x16x32_bf16(ah, bl[0][kg], acc0, 0, 0, 0);
      acc1 = __builtin_amdgcn_mfma_f32_16x16x32_bf16(ah, bh[1][kg], acc1, 0, 0, 0);
      acc1 = __builtin_amdgcn_mfma_f32_16x16x32_bf16(al, bh[1][kg], acc1, 0, 0, 0);
      acc1 = __builtin_amdgcn_mfma_f32_16x16x32_bf16(ah, bl[1][kg], acc1, 0, 0, 0);
    }

    // ---- packed store: lane holds o = ot*16 + lg*4 + (0..3) for its node ----
    const int ob = ot * 16 + lg * 4;
    {
      const int node = nb + lr;
      union { uint2 u; __half2 h[2]; } pk;
      pk.h[0] = __floats2half2_rn(acc0[0], acc0[1]);
      pk.h[1] = __floats2half2_rn(acc0[2], acc0[3]);
      *(uint2*)(UV + (size_t)node * 256 + ob) = pk.u;
    }
    {
      const int node = nb + 16 + lr;
      union { uint2 u; __half2 h[2]; } pk;
      pk.h[0] = __floats2half2_rn(acc1[0], acc1[1]);
      pk.h[1] = __floats2half2_rn(acc1[2], acc1[3]);
      *(uint2*)(UV + (size_t)node * 256 + ob) = pk.u;
    }
  }
}

// ---------------------------------------------------------------------------
// Stage 2 (v3): PROVEN 16-lane layout (r12) — one uint4 U + one uint4 V per
// lane, 4 contiguous 256B rows per wave-instruction — single dispatch, with
// non-temporal hints on the streaming idx loads / out stores so they do not
// evict UV from L2 (stage 2 is L2-miss-traffic-bound: dur ~ FETCH/3.6TB/s).
// ---------------------------------------------------------------------------
__global__ __launch_bounds__(256) void edge_decode_f16v3_kernel(
    const int* __restrict__ eidx, const __half* __restrict__ UV,
    const float* __restrict__ b1, const float* __restrict__ W2,
    const float* __restrict__ b2, float* __restrict__ out) {
  const int lane = threadIdx.x & 15;
  const int qw = (blockIdx.x * 256 + threadIdx.x) >> 4;
  const int nqw = (gridDim.x * 256) >> 4;

  const float4 b1a = ((const float4*)b1)[2 * lane];
  const float4 b1b = ((const float4*)b1)[2 * lane + 1];
  const float4 w2a = ((const float4*)W2)[2 * lane];
  const float4 w2b = ((const float4*)W2)[2 * lane + 1];
  const float bb[8] = {b1a.x, b1a.y, b1a.z, b1a.w, b1b.x, b1b.y, b1b.z, b1b.w};
  const float ww[8] = {w2a.x, w2a.y, w2a.z, w2a.w, w2b.x, w2b.y, w2b.z, w2b.w};
  const float bias2 = b2[0];

  const int* __restrict__ rows = eidx;
  const int* __restrict__ cols = eidx + NE;

#pragma unroll 2
  for (int e = qw; e < NE; e += nqw) {
    const int r = __builtin_nontemporal_load(rows + e);
    const int c = __builtin_nontemporal_load(cols + e);
    union { uint4 u; __half2 h[4]; } Uu, Vv;
    Uu.u = *(const uint4*)(UV + (size_t)r * 256 + lane * 8);
    Vv.u = *(const uint4*)(UV + (size_t)c * 256 + 128 + lane * 8);

    float s = 0.f;
#pragma unroll
    for (int k = 0; k < 4; ++k) {
      const float2 uf = __half22float2(Uu.h[k]);
      const float2 vf = __half22float2(Vv.h[k]);
      float t0 = uf.x + vf.x + bb[2 * k];
      t0 = (t0 >= 0.f) ? t0 : 0.01f * t0;
      s = fmaf(t0, ww[2 * k], s);
      float t1 = uf.y + vf.y + bb[2 * k + 1];
      t1 = (t1 >= 0.f) ? t1 : 0.01f * t1;
      s = fmaf(t1, ww[2 * k + 1], s);
    }

    s += __shfl_xor(s, 8);
    s += __shfl_xor(s, 4);
    s += __shfl_xor(s, 2);
    s += __shfl_xor(s, 1);
    if (lane == 0) __builtin_nontemporal_store(s + bias2, out + e);
  }
}

// ---------------------------------------------------------------------------
// Fallback (only if workspace is too small): direct per-edge fp32 compute.
// ---------------------------------------------------------------------------
__global__ __launch_bounds__(64) void edge_direct_kernel(
    const float* __restrict__ z, const int* __restrict__ eidx,
    const float* __restrict__ W1, const float* __restrict__ b1,
    const float* __restrict__ W2, const float* __restrict__ b2,
    float* __restrict__ out) {
  const int lane = threadIdx.x;
  const int o0 = lane, o1 = lane + 64;
  const float w2_0 = W2[o0], w2_1 = W2[o1];
  const float b1_0 = b1[o0], b1_1 = b1[o1];
  const float bias2 = b2[0];

  for (int e = blockIdx.x; e < NE; e += gridDim.x) {
    const int r = eidx[e];
    const int c = eidx[e + NE];
    const float* __restrict__ zr = z + (size_t)r * HC;
    const float* __restrict__ zc = z + (size_t)c * HC;
    float a0 = 0.f, a1 = 0.f;
    for (int h = 0; h < HC; ++h) {
      const float zrh = zr[h], zch = zc[h];
      a0 = fmaf(zrh, W1[(size_t)o0 * 256 + h], a0);
      a0 = fmaf(zch, W1[(size_t)o0 * 256 + 128 + h], a0);
      a1 = fmaf(zrh, W1[(size_t)o1 * 256 + h], a1);
      a1 = fmaf(zch, W1[(size_t)o1 * 256 + 128 + h], a1);
    }
    a0 += b1_0; a1 += b1_1;
    a0 = (a0 >= 0.f) ? a0 : 0.01f * a0;
    a1 = (a1 >= 0.f) ? a1 : 0.01f * a1;
    float s = fmaf(a0, w2_0, a1 * w2_1);
    for (int off = 32; off >= 1; off >>= 1) s += __shfl_xor(s, off);
    if (lane == 0) out[e] = s + bias2;
  }
}

extern "C" void kernel_launch(void* const* d_in, const int* in_sizes, int n_in,
                              void* d_out, int out_size, void* d_ws, size_t ws_size,
                              hipStream_t stream) {
  const float* z  = (const float*)d_in[0];
  const int*   ei = (const int*)d_in[1];
  const float* W1 = (const float*)d_in[2];
  const float* b1 = (const float*)d_in[3];
  const float* W2 = (const float*)d_in[4];
  const float* b2 = (const float*)d_in[5];
  float* out = (float*)d_out;

  const size_t uv_bytes = (size_t)NN * 256 * sizeof(__half);          // 51,200,000
  const size_t w_bytes  = (size_t)256 * 128 * sizeof(unsigned short); // 65,536 each

  if (ws_size >= uv_bytes + 2 * w_bytes) {
    __half* UV = (__half*)d_ws;
    unsigned short* Whf = (unsigned short*)((char*)d_ws + uv_bytes);
    unsigned short* Wlf = Whf + 256 * 128;
    wprep2_kernel<<<16, 256, 0, stream>>>(W1, Whf, Wlf);
    precompute_uv_mfma5_kernel<<<NN / 32, 256, 0, stream>>>(z, Whf, Wlf, UV);
    edge_decode_f16v3_kernel<<<2048, 256, 0, stream>>>(ei, UV, b1, W2, b2, out);
  } else {
    edge_direct_kernel<<<8192, 64, 0, stream>>>(z, ei, W1, b1, W2, b2, out);
  }
}